// Round 2
// baseline (646.218 us; speedup 1.0000x reference)
//
#include <hip/hip_runtime.h>
#include <hip/hip_bf16.h>

#define EMB 2048
#define HEADS 16
#define HDIM 128
#define LATENT 512
#define BATCH 2
#define SEQ 2048
#define MROWS (BATCH*SEQ)   // 4096

typedef __attribute__((ext_vector_type(4))) float f32x4;
typedef __attribute__((ext_vector_type(8))) short s16x8;

__device__ __forceinline__ unsigned short f2bf(float f) {
  __hip_bfloat16 h = __float2bfloat16(f);
  union { __hip_bfloat16 h; unsigned short u; } c; c.h = h; return c.u;
}

#define GLOAD_LDS16(g, l) \
  __builtin_amdgcn_global_load_lds((const __attribute__((address_space(1))) unsigned int*)(g), \
                                   (__attribute__((address_space(3))) unsigned int*)(l), 16, 0, 0)

// ---------------- fp32 -> bf16 conversion ----------------
__global__ void cvt_kernel(const float* __restrict__ src, unsigned short* __restrict__ dst, int n4) {
  int i = blockIdx.x * blockDim.x + threadIdx.x;
  int stride = gridDim.x * blockDim.x;
  for (; i < n4; i += stride) {
    float4 v = reinterpret_cast<const float4*>(src)[i];
    ushort4 o;
    o.x = f2bf(v.x); o.y = f2bf(v.y); o.z = f2bf(v.z); o.w = f2bf(v.w);
    reinterpret_cast<ushort4*>(dst)[i] = o;
  }
}

// ---------------- GEMM: C[M,N] = A[M,K] * B[N,K]^T  (bf16 in, bf16 or f32+bias out) ----------------
#define BM 128
#define BN 128
#define BK 32

template<int OUTF32>
__global__ __launch_bounds__(256) void gemm_bt(
    const unsigned short* __restrict__ A, const unsigned short* __restrict__ B,
    void* __restrict__ C, const float* __restrict__ bias, int M, int N, int K)
{
  __shared__ __align__(16) unsigned short sA[BM][BK];   // linear: required by global_load_lds
  __shared__ __align__(16) unsigned short sB[BN][BK];
  const int tid  = threadIdx.x;
  const int lane = tid & 63, wave = tid >> 6;
  const int wm = wave >> 1, wn = wave & 1;      // 2x2 waves, each 64x64
  const int lrow = lane & 15, kgrp = lane >> 4;
  const long bm = (long)blockIdx.y * BM, bn = (long)blockIdx.x * BN;
  const int srow = tid >> 2;                    // staging row 0..63
  const int scol = (tid & 3) * 8;               // staging col (8 bf16 = 16B)

  f32x4 zero4 = {0.f, 0.f, 0.f, 0.f};
  f32x4 acc[4][4];
  #pragma unroll
  for (int i = 0; i < 4; ++i)
    #pragma unroll
    for (int j = 0; j < 4; ++j) acc[i][j] = zero4;

  const unsigned short* ga = A + (bm + srow) * (long)K + scol;
  const unsigned short* gb = B + (bn + srow) * (long)K + scol;

  for (int k0 = 0; k0 < K; k0 += BK) {
    // stage 128x32 A-tile and B-tile; LDS dest is linear in lane (wave-uniform base + lane*16)
    GLOAD_LDS16(ga + k0,                 &sA[srow][scol]);
    GLOAD_LDS16(ga + 64*(long)K + k0,    &sA[srow + 64][scol]);
    GLOAD_LDS16(gb + k0,                 &sB[srow][scol]);
    GLOAD_LDS16(gb + 64*(long)K + k0,    &sB[srow + 64][scol]);
    __syncthreads();   // compiler drains vmcnt before barrier -> tiles visible

    s16x8 aF[4], bF[4];
    #pragma unroll
    for (int i = 0; i < 4; ++i) {
      aF[i] = *reinterpret_cast<const s16x8*>(&sA[wm*64 + i*16 + lrow][kgrp*8]);
      bF[i] = *reinterpret_cast<const s16x8*>(&sB[wn*64 + i*16 + lrow][kgrp*8]);
    }
    #pragma unroll
    for (int i = 0; i < 4; ++i)
      #pragma unroll
      for (int j = 0; j < 4; ++j)
        acc[i][j] = __builtin_amdgcn_mfma_f32_16x16x32_bf16(aF[i], bF[j], acc[i][j], 0, 0, 0);
    __syncthreads();   // all reads done before next stage overwrites
  }

  // epilogue: D layout col=lane&15, row=(lane>>4)*4+reg (HW-verified)
  #pragma unroll
  for (int i = 0; i < 4; ++i) {
    #pragma unroll
    for (int j = 0; j < 4; ++j) {
      long row = bm + wm*64 + i*16 + kgrp*4;
      long col = bn + wn*64 + j*16 + lrow;
      if (OUTF32) {
        float* Cf = (float*)C;
        float bv = bias[col];
        #pragma unroll
        for (int r = 0; r < 4; ++r) Cf[(row + r) * (long)N + col] = acc[i][j][r] + bv;
      } else {
        unsigned short* Cb = (unsigned short*)C;
        #pragma unroll
        for (int r = 0; r < 4; ++r) Cb[(row + r) * (long)N + col] = f2bf(acc[i][j][r]);
      }
    }
  }
}

// ---------------- causal flash attention ----------------
// grid: (S/64, HEADS, BATCH), 256 threads = 4 waves, each wave owns 16 q rows.
__global__ __launch_bounds__(256) void attn_kernel(
    const unsigned short* __restrict__ Q, const unsigned short* __restrict__ Kg,
    const unsigned short* __restrict__ V, unsigned short* __restrict__ CTX)
{
  const int b = blockIdx.z, h = blockIdx.y;
  const int tid = threadIdx.x, wave = tid >> 6, lane = tid & 63;
  const int lrow = lane & 15, kgrp = lane >> 4;
  const int qs = blockIdx.x * 64 + wave * 16;

  __shared__ __align__(16) unsigned short sK[32][136];    // padded: conflict-light ds_read_b128
  __shared__ __align__(16) unsigned short sVT[128][40];   // V transposed [d][kv]
  __shared__ __align__(16) unsigned short sP[4][16][40];  // per-wave P staging

  // Q fragments: row = qs + (lane&15), k = kk*32 + kgrp*8 + j
  const long qbase = ((long)(b*SEQ + qs + lrow)) * EMB + h*HDIM;
  s16x8 qF[4];
  #pragma unroll
  for (int kk = 0; kk < 4; ++kk)
    qF[kk] = *reinterpret_cast<const s16x8*>(Q + qbase + kk*32 + kgrp*8);

  f32x4 zero4 = {0.f, 0.f, 0.f, 0.f};
  f32x4 o[8];
  #pragma unroll
  for (int dt = 0; dt < 8; ++dt) o[dt] = zero4;
  float rm[4], rl[4];
  #pragma unroll
  for (int r = 0; r < 4; ++r) { rm[r] = -3.0e38f; rl[r] = 0.f; }

  const int kvr = tid >> 3;        // staging: kv row 0..31
  const int d0  = (tid & 7) * 16;  // staging: d offset
  const int ntiles = blockIdx.x * 2 + 2;   // cover causal range of the whole block
  const float scale = 0.08838834764831845f; // 1/sqrt(128)

  for (int t = 0; t < ntiles; ++t) {
    const int kv0 = t * 32;
    __syncthreads();   // previous tile's LDS reads complete
    const long kvbase = ((long)(b*SEQ + kv0 + kvr)) * EMB + h*HDIM + d0;
    s16x8 k0v = *reinterpret_cast<const s16x8*>(Kg + kvbase);
    s16x8 k1v = *reinterpret_cast<const s16x8*>(Kg + kvbase + 8);
    *reinterpret_cast<s16x8*>(&sK[kvr][d0])     = k0v;
    *reinterpret_cast<s16x8*>(&sK[kvr][d0 + 8]) = k1v;
    s16x8 v0v = *reinterpret_cast<const s16x8*>(V + kvbase);
    s16x8 v1v = *reinterpret_cast<const s16x8*>(V + kvbase + 8);
    #pragma unroll
    for (int i = 0; i < 8; ++i) sVT[d0 + i][kvr]     = (unsigned short)v0v[i];
    #pragma unroll
    for (int i = 0; i < 8; ++i) sVT[d0 + 8 + i][kvr] = (unsigned short)v1v[i];
    __syncthreads();

    // QK^T: scores [16 q][32 kv] in two 16x16 accs
    f32x4 sc0 = zero4, sc1 = zero4;
    #pragma unroll
    for (int kk = 0; kk < 4; ++kk) {
      s16x8 kF0 = *reinterpret_cast<const s16x8*>(&sK[lrow][kk*32 + kgrp*8]);
      s16x8 kF1 = *reinterpret_cast<const s16x8*>(&sK[16 + lrow][kk*32 + kgrp*8]);
      sc0 = __builtin_amdgcn_mfma_f32_16x16x32_bf16(qF[kk], kF0, sc0, 0, 0, 0);
      sc1 = __builtin_amdgcn_mfma_f32_16x16x32_bf16(qF[kk], kF1, sc1, 0, 0, 0);
    }

    // scale + causal mask; D layout: col(kv)=lane&15, row(q)=kgrp*4+r
    float s0v[4], s1v[4], tm[4];
    #pragma unroll
    for (int r = 0; r < 4; ++r) {
      int q  = qs + kgrp*4 + r;
      int c0 = kv0 + lrow, c1 = kv0 + 16 + lrow;
      s0v[r] = (c0 <= q) ? sc0[r] * scale : -3.0e38f;
      s1v[r] = (c1 <= q) ? sc1[r] * scale : -3.0e38f;
      tm[r] = fmaxf(s0v[r], s1v[r]);
    }
    #pragma unroll
    for (int m = 1; m < 16; m <<= 1)
      #pragma unroll
      for (int r = 0; r < 4; ++r) tm[r] = fmaxf(tm[r], __shfl_xor(tm[r], m));

    float corr[4], ts[4], p0[4], p1[4];
    #pragma unroll
    for (int r = 0; r < 4; ++r) {
      float mnew = fmaxf(rm[r], tm[r]);
      corr[r] = __expf(rm[r] - mnew);
      rm[r] = mnew;
      p0[r] = __expf(s0v[r] - mnew);
      p1[r] = __expf(s1v[r] - mnew);
      ts[r] = p0[r] + p1[r];
    }
    #pragma unroll
    for (int m = 1; m < 16; m <<= 1)
      #pragma unroll
      for (int r = 0; r < 4; ++r) ts[r] += __shfl_xor(ts[r], m);
    #pragma unroll
    for (int r = 0; r < 4; ++r) rl[r] = rl[r] * corr[r] + ts[r];
    #pragma unroll
    for (int dt = 0; dt < 8; ++dt)
      #pragma unroll
      for (int r = 0; r < 4; ++r) o[dt][r] *= corr[r];

    // P -> LDS (D layout) -> A-fragment (same assumed k-mapping as V fragment)
    #pragma unroll
    for (int r = 0; r < 4; ++r) {
      sP[wave][kgrp*4 + r][lrow]      = f2bf(p0[r]);
      sP[wave][kgrp*4 + r][16 + lrow] = f2bf(p1[r]);
    }
    s16x8 pF = *reinterpret_cast<const s16x8*>(&sP[wave][lrow][kgrp*8]);
    #pragma unroll
    for (int dt = 0; dt < 8; ++dt) {
      s16x8 vF = *reinterpret_cast<const s16x8*>(&sVT[dt*16 + lrow][kgrp*8]);
      o[dt] = __builtin_amdgcn_mfma_f32_16x16x32_bf16(pF, vF, o[dt], 0, 0, 0);
    }
  }

  // write ctx[b, s, h*128 + d], bf16
  #pragma unroll
  for (int dt = 0; dt < 8; ++dt)
    #pragma unroll
    for (int r = 0; r < 4; ++r) {
      long row = (long)(b*SEQ + qs + kgrp*4 + r);
      CTX[row * EMB + h*HDIM + dt*16 + lrow] = f2bf(o[dt][r] / rl[r]);
    }
}

// ---------------- launcher ----------------
extern "C" void kernel_launch(void* const* d_in, const int* in_sizes, int n_in,
                              void* d_out, int out_size, void* d_ws, size_t ws_size,
                              hipStream_t stream)
{
  const float* x      = (const float*)d_in[0];
  const float* w_q    = (const float*)d_in[1];
  const float* w_down = (const float*)d_in[2];
  const float* w_upk  = (const float*)d_in[3];
  const float* w_upv  = (const float*)d_in[4];
  const float* w_out  = (const float*)d_in[5];
  const float* b_out  = (const float*)d_in[6];
  float* out = (float*)d_out;

  char* ws = (char*)d_ws;
  size_t off = 0;
  auto alloc = [&](size_t elems) {
    void* p = ws + off; off += elems * 2; off = (off + 255) & ~(size_t)255; return p;
  };
  unsigned short* xb   = (unsigned short*)alloc((size_t)MROWS * EMB);
  unsigned short* wqb  = (unsigned short*)alloc((size_t)EMB * EMB);
  unsigned short* wdb  = (unsigned short*)alloc((size_t)LATENT * EMB);
  unsigned short* wkb  = (unsigned short*)alloc((size_t)EMB * LATENT);
  unsigned short* wvb  = (unsigned short*)alloc((size_t)EMB * LATENT);
  unsigned short* wob  = (unsigned short*)alloc((size_t)EMB * EMB);
  unsigned short* qb   = (unsigned short*)alloc((size_t)MROWS * EMB);
  unsigned short* latb = (unsigned short*)alloc((size_t)MROWS * LATENT);
  unsigned short* kb   = (unsigned short*)alloc((size_t)MROWS * EMB);
  unsigned short* vb   = (unsigned short*)alloc((size_t)MROWS * EMB);
  unsigned short* ctxb = xb;   // xb dead after first two GEMMs; reuse for ctx

  auto cvt = [&](const float* s, unsigned short* d, size_t n) {
    int n4 = (int)(n / 4);
    int blocks = (n4 + 255) / 256; if (blocks > 1024) blocks = 1024;
    cvt_kernel<<<dim3(blocks), dim3(256), 0, stream>>>(s, d, n4);
  };
  cvt(x,      xb,  (size_t)MROWS * EMB);
  cvt(w_q,    wqb, (size_t)EMB * EMB);
  cvt(w_down, wdb, (size_t)LATENT * EMB);
  cvt(w_upk,  wkb, (size_t)EMB * LATENT);
  cvt(w_upv,  wvb, (size_t)EMB * LATENT);
  cvt(w_out,  wob, (size_t)EMB * EMB);

  gemm_bt<0><<<dim3(EMB/BN,    MROWS/BM), 256, 0, stream>>>(xb,   wqb, qb,   nullptr, MROWS, EMB,    EMB);
  gemm_bt<0><<<dim3(LATENT/BN, MROWS/BM), 256, 0, stream>>>(xb,   wdb, latb, nullptr, MROWS, LATENT, EMB);
  gemm_bt<0><<<dim3(EMB/BN,    MROWS/BM), 256, 0, stream>>>(latb, wkb, kb,   nullptr, MROWS, EMB,    LATENT);
  gemm_bt<0><<<dim3(EMB/BN,    MROWS/BM), 256, 0, stream>>>(latb, wvb, vb,   nullptr, MROWS, EMB,    LATENT);

  attn_kernel<<<dim3(SEQ/64, HEADS, BATCH), 256, 0, stream>>>(qb, kb, vb, ctxb);

  gemm_bt<1><<<dim3(EMB/BN, MROWS/BM), 256, 0, stream>>>(ctxb, wob, (void*)out, b_out, MROWS, EMB, EMB);
}

// Round 3
// 465.109 us; speedup vs baseline: 1.3894x; 1.3894x over previous
//
#include <hip/hip_runtime.h>
#include <hip/hip_bf16.h>

#define EMB 2048
#define HEADS 16
#define HDIM 128
#define LATENT 512
#define BATCH 2
#define SEQ 2048
#define MROWS (BATCH*SEQ)   // 4096

typedef __attribute__((ext_vector_type(4))) float f32x4;
typedef __attribute__((ext_vector_type(8))) short s16x8;

__device__ __forceinline__ unsigned short f2bf(float f) {
  __hip_bfloat16 h = __float2bfloat16(f);
  union { __hip_bfloat16 h; unsigned short u; } c; c.h = h; return c.u;
}

#define GLOAD_LDS16(g, l) \
  __builtin_amdgcn_global_load_lds((const __attribute__((address_space(1))) unsigned int*)(g), \
                                   (__attribute__((address_space(3))) unsigned int*)(l), 16, 0, 0)

// ---------------- fp32 -> bf16 conversion ----------------
__global__ void cvt_kernel(const float* __restrict__ src, unsigned short* __restrict__ dst, int n4) {
  int i = blockIdx.x * blockDim.x + threadIdx.x;
  int stride = gridDim.x * blockDim.x;
  for (; i < n4; i += stride) {
    float4 v = reinterpret_cast<const float4*>(src)[i];
    ushort4 o;
    o.x = f2bf(v.x); o.y = f2bf(v.y); o.z = f2bf(v.z); o.w = f2bf(v.w);
    reinterpret_cast<ushort4*>(dst)[i] = o;
  }
}

// ---------------- GEMM: C[M,N] = A[M,K] * B[N,K]^T ----------------
#define BM 128
#define BN 128
#define BK 32

template<int OUTF32>
__global__ __launch_bounds__(256) void gemm_bt(
    const unsigned short* __restrict__ A, const unsigned short* __restrict__ B,
    void* __restrict__ C, const float* __restrict__ bias, int M, int N, int K)
{
  __shared__ __align__(16) unsigned short sA[BM][BK];
  __shared__ __align__(16) unsigned short sB[BN][BK];
  const int tid  = threadIdx.x;
  const int lane = tid & 63, wave = tid >> 6;
  const int wm = wave >> 1, wn = wave & 1;
  const int lrow = lane & 15, kgrp = lane >> 4;
  const long bm = (long)blockIdx.y * BM, bn = (long)blockIdx.x * BN;
  const int srow = tid >> 2;
  const int scol = (tid & 3) * 8;

  f32x4 zero4 = {0.f, 0.f, 0.f, 0.f};
  f32x4 acc[4][4];
  #pragma unroll
  for (int i = 0; i < 4; ++i)
    #pragma unroll
    for (int j = 0; j < 4; ++j) acc[i][j] = zero4;

  const unsigned short* ga = A + (bm + srow) * (long)K + scol;
  const unsigned short* gb = B + (bn + srow) * (long)K + scol;

  for (int k0 = 0; k0 < K; k0 += BK) {
    GLOAD_LDS16(ga + k0,                 &sA[srow][scol]);
    GLOAD_LDS16(ga + 64*(long)K + k0,    &sA[srow + 64][scol]);
    GLOAD_LDS16(gb + k0,                 &sB[srow][scol]);
    GLOAD_LDS16(gb + 64*(long)K + k0,    &sB[srow + 64][scol]);
    __syncthreads();

    s16x8 aF[4], bF[4];
    #pragma unroll
    for (int i = 0; i < 4; ++i) {
      aF[i] = *reinterpret_cast<const s16x8*>(&sA[wm*64 + i*16 + lrow][kgrp*8]);
      bF[i] = *reinterpret_cast<const s16x8*>(&sB[wn*64 + i*16 + lrow][kgrp*8]);
    }
    #pragma unroll
    for (int i = 0; i < 4; ++i)
      #pragma unroll
      for (int j = 0; j < 4; ++j)
        acc[i][j] = __builtin_amdgcn_mfma_f32_16x16x32_bf16(aF[i], bF[j], acc[i][j], 0, 0, 0);
    __syncthreads();
  }

  #pragma unroll
  for (int i = 0; i < 4; ++i) {
    #pragma unroll
    for (int j = 0; j < 4; ++j) {
      long row = bm + wm*64 + i*16 + kgrp*4;
      long col = bn + wn*64 + j*16 + lrow;
      if (OUTF32) {
        float* Cf = (float*)C;
        float bv = bias[col];
        #pragma unroll
        for (int r = 0; r < 4; ++r) Cf[(row + r) * (long)N + col] = acc[i][j][r] + bv;
      } else {
        unsigned short* Cb = (unsigned short*)C;
        #pragma unroll
        for (int r = 0; r < 4; ++r) Cb[(row + r) * (long)N + col] = f2bf(acc[i][j][r]);
      }
    }
  }
}

// ---------------- causal flash attention v2 ----------------
// 256 blocks (8 pairs x 16 heads x 2 batch), 256 threads = 4 waves.
// Block processes q-tiles {15-pr, pr} (128 rows each) sequentially: uniform 34 KV-tiles.
// Wave owns 32 q rows (2 x 16-row groups). KVBLK=64. K in LDS (XOR-swizzled via
// pre-swizzled global_load_lds source). V^T consumed directly from global (L2).
#define KVB 64
#define QTILE 128
#define NQT (SEQ/QTILE)   // 16

__global__ __launch_bounds__(256, 1) void attn2_kernel(
    const unsigned short* __restrict__ Q, const unsigned short* __restrict__ Kg,
    const unsigned short* __restrict__ Vt, unsigned short* __restrict__ CTX)
{
  const int b = blockIdx.z, h = blockIdx.y, pr = blockIdx.x;
  const int tid = threadIdx.x, w = tid >> 6, lane = tid & 63;
  const int lrow = lane & 15, kgrp = lane >> 4;
  const size_t bS = (size_t)b * SEQ;

  __shared__ __align__(16) unsigned short sK[2][KVB * HDIM];  // 32 KB, swizzled content
  __shared__ __align__(16) unsigned short sP[4][32][72];      // 18 KB, per-wave P

  // K staging: thread t stages 16B to LDS slot t*16 (+R*4096), 4 rounds of 16 rows.
  // LDS[p] = logical[p ^ ((row(p)&7)<<4)]  (st-16-slot XOR swizzle, rows of 256B)
  const int krow  = tid >> 4;                                    // 0..15
  const int kcolB = ((tid & 15) * 16) ^ (((tid >> 4) & 7) << 4); // pre-swizzled source col (bytes)
  const unsigned short* kst_g = Kg + (bS + krow) * EMB + h * HDIM + (kcolB >> 1);

  // swizzled K-frag read offsets (elements): row r -> r*128 + cc[kk], cc = (colB ^ ((r&7)<<4))/2
  const int swz = (lrow & 7) << 4;
  int cc[4];
  #pragma unroll
  for (int kk = 0; kk < 4; ++kk) cc[kk] = ((kk * 64 + kgrp * 16) ^ swz) >> 1;

  const float C = 0.12751742f;  // log2(e) / sqrt(128)
  f32x4 zero4 = {0.f, 0.f, 0.f, 0.f};

  const int qts[2] = {NQT - 1 - pr, pr};
  for (int ps = 0; ps < 2; ++ps) {
    const int qt = qts[ps];
    const int nt = 2 * qt + 2;
    const int qw = qt * QTILE + w * 32;

    // Q fragments: 2 groups x 16 rows
    s16x8 qF[2][4];
    #pragma unroll
    for (int g = 0; g < 2; ++g)
      #pragma unroll
      for (int kk = 0; kk < 4; ++kk)
        qF[g][kk] = *reinterpret_cast<const s16x8*>(
            Q + (bS + qw + g * 16 + lrow) * EMB + h * HDIM + kk * 32 + kgrp * 8);

    f32x4 o[2][8];
    float rm[2][4], rl[2][4];
    #pragma unroll
    for (int g = 0; g < 2; ++g) {
      #pragma unroll
      for (int dt = 0; dt < 8; ++dt) o[g][dt] = zero4;
      #pragma unroll
      for (int r = 0; r < 4; ++r) { rm[g][r] = -1.0e30f; rl[g][r] = 0.f; }
    }

    __syncthreads();   // pass boundary: everyone done with previous buffers
    {
      unsigned short* l0 = &sK[0][0] + tid * 8;
      #pragma unroll
      for (int R = 0; R < 4; ++R) GLOAD_LDS16(kst_g + (size_t)R * 16 * EMB, l0 + R * 2048);
    }

    for (int j = 0; j < nt; ++j) {
      __syncthreads();   // tile j staged & visible; prev-tile reads done
      const int kv0 = j * KVB;
      if (j + 1 < nt) {
        const unsigned short* gs = kst_g + (size_t)(j + 1) * KVB * EMB;
        unsigned short* ls = &sK[(j + 1) & 1][0] + tid * 8;
        #pragma unroll
        for (int R = 0; R < 4; ++R) GLOAD_LDS16(gs + (size_t)R * 16 * EMB, ls + R * 2048);
      }

      // V^T B-fragments straight from global (row f=h*128+d, col bS+kv)
      s16x8 vF[2][8];
      #pragma unroll
      for (int hf = 0; hf < 2; ++hf)
        #pragma unroll
        for (int dt = 0; dt < 8; ++dt)
          vF[hf][dt] = *reinterpret_cast<const s16x8*>(
              Vt + (size_t)(h * HDIM + dt * 16 + lrow) * MROWS + bS + kv0 + hf * 32 + kgrp * 8);

      // QK^T: 2 q-groups x 4 kv-groups
      const unsigned short* kb = &sK[j & 1][0];
      f32x4 sc[2][4];
      #pragma unroll
      for (int g = 0; g < 2; ++g)
        #pragma unroll
        for (int kvg = 0; kvg < 4; ++kvg) sc[g][kvg] = zero4;
      #pragma unroll
      for (int kvg = 0; kvg < 4; ++kvg) {
        const int rb = (kvg * 16 + lrow) * HDIM;
        #pragma unroll
        for (int kk = 0; kk < 4; ++kk) {
          s16x8 kF = *reinterpret_cast<const s16x8*>(kb + rb + cc[kk]);
          sc[0][kvg] = __builtin_amdgcn_mfma_f32_16x16x32_bf16(qF[0][kk], kF, sc[0][kvg], 0, 0, 0);
          sc[1][kvg] = __builtin_amdgcn_mfma_f32_16x16x32_bf16(qF[1][kk], kF, sc[1][kvg], 0, 0, 0);
        }
      }

      // online softmax (base-2 domain), per q-group
      #pragma unroll
      for (int g = 0; g < 2; ++g) {
        const bool needm = (kv0 + 63 > qw + g * 16);
        float sv[4][4];
        #pragma unroll
        for (int kvg = 0; kvg < 4; ++kvg)
          #pragma unroll
          for (int r = 0; r < 4; ++r) {
            float s = sc[g][kvg][r];
            if (needm) {
              int qq  = qw + g * 16 + kgrp * 4 + r;
              int col = kv0 + kvg * 16 + lrow;
              s = (col <= qq) ? s : -3.0e38f;
            }
            sv[kvg][r] = s;
          }
        float tm[4];
        #pragma unroll
        for (int r = 0; r < 4; ++r)
          tm[r] = fmaxf(fmaxf(sv[0][r], sv[1][r]), fmaxf(sv[2][r], sv[3][r]));
        #pragma unroll
        for (int m = 1; m < 16; m <<= 1)
          #pragma unroll
          for (int r = 0; r < 4; ++r) tm[r] = fmaxf(tm[r], __shfl_xor(tm[r], m));

        float corr[4], ts[4];
        #pragma unroll
        for (int r = 0; r < 4; ++r) {
          float mn = fmaxf(rm[g][r], tm[r] * C);
          corr[r] = exp2f(rm[g][r] - mn);
          rm[g][r] = mn;
          float p0 = exp2f(fmaf(sv[0][r], C, -mn));
          float p1 = exp2f(fmaf(sv[1][r], C, -mn));
          float p2 = exp2f(fmaf(sv[2][r], C, -mn));
          float p3 = exp2f(fmaf(sv[3][r], C, -mn));
          ts[r] = (p0 + p1) + (p2 + p3);
          const int qrow = g * 16 + kgrp * 4 + r;
          sP[w][qrow][ 0 + lrow] = f2bf(p0);
          sP[w][qrow][16 + lrow] = f2bf(p1);
          sP[w][qrow][32 + lrow] = f2bf(p2);
          sP[w][qrow][48 + lrow] = f2bf(p3);
        }
        #pragma unroll
        for (int m = 1; m < 16; m <<= 1)
          #pragma unroll
          for (int r = 0; r < 4; ++r) ts[r] += __shfl_xor(ts[r], m);
        #pragma unroll
        for (int r = 0; r < 4; ++r) rl[g][r] = rl[g][r] * corr[r] + ts[r];
        #pragma unroll
        for (int dt = 0; dt < 8; ++dt)
          #pragma unroll
          for (int r = 0; r < 4; ++r) o[g][dt][r] *= corr[r];
      }

      // PV: A = P (LDS, per-wave), B = V^T (regs)
      s16x8 pF[2][2];
      #pragma unroll
      for (int g = 0; g < 2; ++g)
        #pragma unroll
        for (int hf = 0; hf < 2; ++hf)
          pF[g][hf] = *reinterpret_cast<const s16x8*>(&sP[w][g * 16 + lrow][hf * 32 + kgrp * 8]);
      #pragma unroll
      for (int g = 0; g < 2; ++g)
        #pragma unroll
        for (int dt = 0; dt < 8; ++dt) {
          o[g][dt] = __builtin_amdgcn_mfma_f32_16x16x32_bf16(pF[g][0], vF[0][dt], o[g][dt], 0, 0, 0);
          o[g][dt] = __builtin_amdgcn_mfma_f32_16x16x32_bf16(pF[g][1], vF[1][dt], o[g][dt], 0, 0, 0);
        }
    }

    // epilogue: ctx[b, q, h*128+d]
    #pragma unroll
    for (int g = 0; g < 2; ++g) {
      float iv[4];
      #pragma unroll
      for (int r = 0; r < 4; ++r) iv[r] = 1.0f / rl[g][r];
      #pragma unroll
      for (int dt = 0; dt < 8; ++dt)
        #pragma unroll
        for (int r = 0; r < 4; ++r)
          CTX[(bS + qw + g * 16 + kgrp * 4 + r) * EMB + h * HDIM + dt * 16 + lrow] =
              f2bf(o[g][dt][r] * iv[r]);
    }
  }
}

// ---------------- launcher ----------------
extern "C" void kernel_launch(void* const* d_in, const int* in_sizes, int n_in,
                              void* d_out, int out_size, void* d_ws, size_t ws_size,
                              hipStream_t stream)
{
  const float* x      = (const float*)d_in[0];
  const float* w_q    = (const float*)d_in[1];
  const float* w_down = (const float*)d_in[2];
  const float* w_upk  = (const float*)d_in[3];
  const float* w_upv  = (const float*)d_in[4];
  const float* w_out  = (const float*)d_in[5];
  const float* b_out  = (const float*)d_in[6];
  float* out = (float*)d_out;

  char* ws = (char*)d_ws;
  size_t off = 0;
  auto alloc = [&](size_t elems) {
    void* p = ws + off; off += elems * 2; off = (off + 255) & ~(size_t)255; return p;
  };
  unsigned short* xb   = (unsigned short*)alloc((size_t)MROWS * EMB);
  unsigned short* wqb  = (unsigned short*)alloc((size_t)EMB * EMB);
  unsigned short* wdb  = (unsigned short*)alloc((size_t)LATENT * EMB);
  unsigned short* wkb  = (unsigned short*)alloc((size_t)EMB * LATENT);
  unsigned short* wvb  = (unsigned short*)alloc((size_t)EMB * LATENT);
  unsigned short* wob  = (unsigned short*)alloc((size_t)EMB * EMB);
  unsigned short* qb   = (unsigned short*)alloc((size_t)MROWS * EMB);
  unsigned short* latb = (unsigned short*)alloc((size_t)MROWS * LATENT);
  unsigned short* kb   = (unsigned short*)alloc((size_t)MROWS * EMB);
  unsigned short* vtb  = (unsigned short*)alloc((size_t)EMB * MROWS);  // V^T [2048][4096]
  unsigned short* ctxb = xb;   // xb dead after first two GEMMs; reuse for ctx

  auto cvt = [&](const float* s, unsigned short* d, size_t n) {
    int n4 = (int)(n / 4);
    int blocks = (n4 + 255) / 256; if (blocks > 1024) blocks = 1024;
    cvt_kernel<<<dim3(blocks), dim3(256), 0, stream>>>(s, d, n4);
  };
  cvt(x,      xb,  (size_t)MROWS * EMB);
  cvt(w_q,    wqb, (size_t)EMB * EMB);
  cvt(w_down, wdb, (size_t)LATENT * EMB);
  cvt(w_upk,  wkb, (size_t)EMB * LATENT);
  cvt(w_upv,  wvb, (size_t)EMB * LATENT);
  cvt(w_out,  wob, (size_t)EMB * EMB);

  gemm_bt<0><<<dim3(EMB/BN,    MROWS/BM), 256, 0, stream>>>(xb,   wqb, qb,   nullptr, MROWS, EMB,    EMB);
  gemm_bt<0><<<dim3(LATENT/BN, MROWS/BM), 256, 0, stream>>>(xb,   wdb, latb, nullptr, MROWS, LATENT, EMB);
  gemm_bt<0><<<dim3(EMB/BN,    MROWS/BM), 256, 0, stream>>>(latb, wkb, kb,   nullptr, MROWS, EMB,    LATENT);
  // V^T = w_up_v @ latent^T  : [EMB][MROWS] — feeds attention's PV directly, no transpose
  gemm_bt<0><<<dim3(MROWS/BN,  EMB/BM),   256, 0, stream>>>(wvb,  latb, vtb, nullptr, EMB,   MROWS,  LATENT);

  attn2_kernel<<<dim3(NQT/2, HEADS, BATCH), 256, 0, stream>>>(qb, kb, vtb, ctxb);

  gemm_bt<1><<<dim3(EMB/BN, MROWS/BM), 256, 0, stream>>>(ctxb, wob, (void*)out, b_out, MROWS, EMB, EMB);
}

// Round 4
// 454.851 us; speedup vs baseline: 1.4207x; 1.0226x over previous
//
#include <hip/hip_runtime.h>
#include <hip/hip_bf16.h>

#define EMB 2048
#define HEADS 16
#define HDIM 128
#define LATENT 512
#define BATCH 2
#define SEQ 2048
#define MROWS (BATCH*SEQ)   // 4096

typedef __attribute__((ext_vector_type(4))) float f32x4;
typedef __attribute__((ext_vector_type(8))) short s16x8;

__device__ __forceinline__ unsigned short f2bf(float f) {
  __hip_bfloat16 h = __float2bfloat16(f);
  union { __hip_bfloat16 h; unsigned short u; } c; c.h = h; return c.u;
}

#define GLOAD_LDS16(g, l) \
  __builtin_amdgcn_global_load_lds((const __attribute__((address_space(1))) unsigned int*)(g), \
                                   (__attribute__((address_space(3))) unsigned int*)(l), 16, 0, 0)

// ---------------- fp32 -> bf16 conversion ----------------
__global__ void cvt_kernel(const float* __restrict__ src, unsigned short* __restrict__ dst, int n4) {
  int i = blockIdx.x * blockDim.x + threadIdx.x;
  int stride = gridDim.x * blockDim.x;
  for (; i < n4; i += stride) {
    float4 v = reinterpret_cast<const float4*>(src)[i];
    ushort4 o;
    o.x = f2bf(v.x); o.y = f2bf(v.y); o.z = f2bf(v.z); o.w = f2bf(v.w);
    reinterpret_cast<ushort4*>(dst)[i] = o;
  }
}

// ---------------- GEMM: C[M,N] = A[M,K] * B[N,K]^T ----------------
#define BM 128
#define BN 128
#define BK 32

template<int OUTF32>
__global__ __launch_bounds__(256) void gemm_bt(
    const unsigned short* __restrict__ A, const unsigned short* __restrict__ B,
    void* __restrict__ C, const float* __restrict__ bias, int M, int N, int K)
{
  __shared__ __align__(16) unsigned short sA[BM][BK];
  __shared__ __align__(16) unsigned short sB[BN][BK];
  const int tid  = threadIdx.x;
  const int lane = tid & 63, wave = tid >> 6;
  const int wm = wave >> 1, wn = wave & 1;
  const int lrow = lane & 15, kgrp = lane >> 4;

  // T1: XCD-aware bijective swizzle (all grids here have nwg % 8 == 0)
  const int gx = gridDim.x;
  const int nwg = gx * gridDim.y;
  const int orig = blockIdx.y * gx + blockIdx.x;
  const int chunk = nwg >> 3;
  const int sw = (orig & 7) * chunk + (orig >> 3);
  const long bm = (long)(sw / gx) * BM, bn = (long)(sw % gx) * BN;

  const int srow = tid >> 2;
  const int scol = (tid & 3) * 8;

  f32x4 zero4 = {0.f, 0.f, 0.f, 0.f};
  f32x4 acc[4][4];
  #pragma unroll
  for (int i = 0; i < 4; ++i)
    #pragma unroll
    for (int j = 0; j < 4; ++j) acc[i][j] = zero4;

  const unsigned short* ga = A + (bm + srow) * (long)K + scol;
  const unsigned short* gb = B + (bn + srow) * (long)K + scol;

  for (int k0 = 0; k0 < K; k0 += BK) {
    GLOAD_LDS16(ga + k0,                 &sA[srow][scol]);
    GLOAD_LDS16(ga + 64*(long)K + k0,    &sA[srow + 64][scol]);
    GLOAD_LDS16(gb + k0,                 &sB[srow][scol]);
    GLOAD_LDS16(gb + 64*(long)K + k0,    &sB[srow + 64][scol]);
    __syncthreads();

    s16x8 aF[4], bF[4];
    #pragma unroll
    for (int i = 0; i < 4; ++i) {
      aF[i] = *reinterpret_cast<const s16x8*>(&sA[wm*64 + i*16 + lrow][kgrp*8]);
      bF[i] = *reinterpret_cast<const s16x8*>(&sB[wn*64 + i*16 + lrow][kgrp*8]);
    }
    #pragma unroll
    for (int i = 0; i < 4; ++i)
      #pragma unroll
      for (int j = 0; j < 4; ++j)
        acc[i][j] = __builtin_amdgcn_mfma_f32_16x16x32_bf16(aF[i], bF[j], acc[i][j], 0, 0, 0);
    __syncthreads();
  }

  #pragma unroll
  for (int i = 0; i < 4; ++i) {
    #pragma unroll
    for (int j = 0; j < 4; ++j) {
      long row = bm + wm*64 + i*16 + kgrp*4;
      long col = bn + wn*64 + j*16 + lrow;
      if (OUTF32) {
        float* Cf = (float*)C;
        float bv = bias[col];
        #pragma unroll
        for (int r = 0; r < 4; ++r) Cf[(row + r) * (long)N + col] = acc[i][j][r] + bv;
      } else {
        unsigned short* Cb = (unsigned short*)C;
        #pragma unroll
        for (int r = 0; r < 4; ++r) Cb[(row + r) * (long)N + col] = f2bf(acc[i][j][r]);
      }
    }
  }
}

// ---------------- causal flash attention v3 ----------------
// Grid (16,16,2) = 512 blocks, 256 threads = 4 waves, each wave owns 16 q rows.
// Block does q-tiles {31-pr, pr} (64 rows each) sequentially: uniform 33 KV-tiles.
// K in LDS (XOR-swizzled via pre-swizzled global_load_lds source), double-buffered.
// V^T consumed directly from global (L2-resident). P through per-wave LDS.
#define KVB 64
#define QTB 64
#define NQT3 (SEQ/QTB)   // 32

__global__ __launch_bounds__(256, 2) void attn3_kernel(
    const unsigned short* __restrict__ Q, const unsigned short* __restrict__ Kg,
    const unsigned short* __restrict__ Vt, unsigned short* __restrict__ CTX)
{
  const int pr = blockIdx.x, h = blockIdx.y, b = blockIdx.z;
  const int tid = threadIdx.x, w = tid >> 6, lane = tid & 63;
  const int lrow = lane & 15, kgrp = lane >> 4;
  const size_t bS = (size_t)b * SEQ;

  __shared__ __align__(16) unsigned short sK[2][KVB * HDIM];  // 32 KB, swizzled content
  __shared__ __align__(16) unsigned short sP[4][16][72];      // 9 KB, per-wave P

  // K staging: thread t stages 16B; 4 rounds of 16 rows. Pre-swizzled source col.
  const int krow  = tid >> 4;                                    // 0..15
  const int kcolB = ((tid & 15) * 16) ^ (((tid >> 4) & 7) << 4); // swizzled col (bytes)
  const unsigned short* kst_g = Kg + (bS + krow) * EMB + h * HDIM + (kcolB >> 1);

  // swizzled K-frag read offsets (elements)
  const int swz = (lrow & 7) << 4;
  int cc[4];
  #pragma unroll
  for (int kk = 0; kk < 4; ++kk) cc[kk] = ((kk * 64 + kgrp * 16) ^ swz) >> 1;

  const float C = 0.12751742f;  // log2(e)/sqrt(128)
  const float THR = 11.5f;      // defer-max threshold (~8 nats) in log2 domain
  f32x4 zero4 = {0.f, 0.f, 0.f, 0.f};

  const int qts[2] = {NQT3 - 1 - pr, pr};
  for (int ps = 0; ps < 2; ++ps) {
    const int qt = qts[ps];
    const int nt = qt + 1;
    const int qw = qt * QTB + w * 16;

    s16x8 qF[4];
    #pragma unroll
    for (int kk = 0; kk < 4; ++kk)
      qF[kk] = *reinterpret_cast<const s16x8*>(
          Q + (bS + qw + lrow) * EMB + h * HDIM + kk * 32 + kgrp * 8);

    f32x4 o[8];
    #pragma unroll
    for (int dt = 0; dt < 8; ++dt) o[dt] = zero4;
    float rm[4], rl[4];
    #pragma unroll
    for (int r = 0; r < 4; ++r) { rm[r] = -1.0e30f; rl[r] = 0.f; }

    __syncthreads();   // pass boundary: prior reads of sK complete
    {
      unsigned short* l0 = &sK[0][0] + tid * 8;
      #pragma unroll
      for (int R = 0; R < 4; ++R) GLOAD_LDS16(kst_g + (size_t)R * 16 * EMB, l0 + R * 2048);
    }

    for (int j = 0; j < nt; ++j) {
      __syncthreads();   // tile j staged & visible; prev-tile reads done
      const int kv0 = j * KVB;
      if (j + 1 < nt) {
        const unsigned short* gs = kst_g + (size_t)(j + 1) * KVB * EMB;
        unsigned short* ls = &sK[(j + 1) & 1][0] + tid * 8;
        #pragma unroll
        for (int R = 0; R < 4; ++R) GLOAD_LDS16(gs + (size_t)R * 16 * EMB, ls + R * 2048);
      }

      // V^T B-fragments straight from global (L2)
      s16x8 vF[2][8];
      #pragma unroll
      for (int hf = 0; hf < 2; ++hf)
        #pragma unroll
        for (int dt = 0; dt < 8; ++dt)
          vF[hf][dt] = *reinterpret_cast<const s16x8*>(
              Vt + (size_t)(h * HDIM + dt * 16 + lrow) * MROWS + bS + kv0 + hf * 32 + kgrp * 8);

      // QK^T: 4 kv-groups x K=128
      const unsigned short* kb = &sK[j & 1][0];
      f32x4 sc[4];
      #pragma unroll
      for (int kvg = 0; kvg < 4; ++kvg) sc[kvg] = zero4;
      __builtin_amdgcn_s_setprio(1);
      #pragma unroll
      for (int kvg = 0; kvg < 4; ++kvg) {
        const int rb = (kvg * 16 + lrow) * HDIM;
        #pragma unroll
        for (int kk = 0; kk < 4; ++kk) {
          s16x8 kF = *reinterpret_cast<const s16x8*>(kb + rb + cc[kk]);
          sc[kvg] = __builtin_amdgcn_mfma_f32_16x16x32_bf16(qF[kk], kF, sc[kvg], 0, 0, 0);
        }
      }
      __builtin_amdgcn_s_setprio(0);

      // mask + online softmax (base-2)
      const bool needm = (kv0 + 63 > qw);
      float sv[4][4];
      #pragma unroll
      for (int kvg = 0; kvg < 4; ++kvg)
        #pragma unroll
        for (int r = 0; r < 4; ++r) {
          float s = sc[kvg][r];
          if (needm) {
            int qq  = qw + kgrp * 4 + r;
            int col = kv0 + kvg * 16 + lrow;
            s = (col <= qq) ? s : -3.0e38f;
          }
          sv[kvg][r] = s;
        }
      float tm[4];
      #pragma unroll
      for (int r = 0; r < 4; ++r)
        tm[r] = fmaxf(fmaxf(sv[0][r], sv[1][r]), fmaxf(sv[2][r], sv[3][r]));
      #pragma unroll
      for (int m = 1; m < 16; m <<= 1)
        #pragma unroll
        for (int r = 0; r < 4; ++r) tm[r] = fmaxf(tm[r], __shfl_xor(tm[r], m));

      // defer-max (T13): skip O-rescale if max growth small (wave-uniform)
      float d = tm[0] * C - rm[0];
      #pragma unroll
      for (int r = 1; r < 4; ++r) d = fmaxf(d, tm[r] * C - rm[r]);
      const bool skip = __all(d <= THR);

      float mn[4];
      #pragma unroll
      for (int r = 0; r < 4; ++r) mn[r] = skip ? rm[r] : fmaxf(rm[r], tm[r] * C);

      float ts[4];
      #pragma unroll
      for (int r = 0; r < 4; ++r) {
        float p0 = exp2f(fmaf(sv[0][r], C, -mn[r]));
        float p1 = exp2f(fmaf(sv[1][r], C, -mn[r]));
        float p2 = exp2f(fmaf(sv[2][r], C, -mn[r]));
        float p3 = exp2f(fmaf(sv[3][r], C, -mn[r]));
        ts[r] = (p0 + p1) + (p2 + p3);
        const int qrow = kgrp * 4 + r;
        sP[w][qrow][ 0 + lrow] = f2bf(p0);
        sP[w][qrow][16 + lrow] = f2bf(p1);
        sP[w][qrow][32 + lrow] = f2bf(p2);
        sP[w][qrow][48 + lrow] = f2bf(p3);
      }
      #pragma unroll
      for (int m = 1; m < 16; m <<= 1)
        #pragma unroll
        for (int r = 0; r < 4; ++r) ts[r] += __shfl_xor(ts[r], m);

      if (skip) {
        #pragma unroll
        for (int r = 0; r < 4; ++r) rl[r] += ts[r];
      } else {
        float corr[4];
        #pragma unroll
        for (int r = 0; r < 4; ++r) {
          corr[r] = exp2f(rm[r] - mn[r]);
          rm[r] = mn[r];
          rl[r] = rl[r] * corr[r] + ts[r];
        }
        #pragma unroll
        for (int dt = 0; dt < 8; ++dt)
          #pragma unroll
          for (int r = 0; r < 4; ++r) o[dt][r] *= corr[r];
      }

      // PV: A = P (LDS, per-wave), B = V^T (regs)
      s16x8 pF[2];
      #pragma unroll
      for (int hf = 0; hf < 2; ++hf)
        pF[hf] = *reinterpret_cast<const s16x8*>(&sP[w][lrow][hf * 32 + kgrp * 8]);
      __builtin_amdgcn_s_setprio(1);
      #pragma unroll
      for (int dt = 0; dt < 8; ++dt) {
        o[dt] = __builtin_amdgcn_mfma_f32_16x16x32_bf16(pF[0], vF[0][dt], o[dt], 0, 0, 0);
        o[dt] = __builtin_amdgcn_mfma_f32_16x16x32_bf16(pF[1], vF[1][dt], o[dt], 0, 0, 0);
      }
      __builtin_amdgcn_s_setprio(0);
    }

    // epilogue
    float iv[4];
    #pragma unroll
    for (int r = 0; r < 4; ++r) iv[r] = 1.0f / rl[r];
    #pragma unroll
    for (int dt = 0; dt < 8; ++dt)
      #pragma unroll
      for (int r = 0; r < 4; ++r)
        CTX[(bS + qw + kgrp * 4 + r) * EMB + h * HDIM + dt * 16 + lrow] =
            f2bf(o[dt][r] * iv[r]);
  }
}

// ---------------- launcher ----------------
extern "C" void kernel_launch(void* const* d_in, const int* in_sizes, int n_in,
                              void* d_out, int out_size, void* d_ws, size_t ws_size,
                              hipStream_t stream)
{
  const float* x      = (const float*)d_in[0];
  const float* w_q    = (const float*)d_in[1];
  const float* w_down = (const float*)d_in[2];
  const float* w_upk  = (const float*)d_in[3];
  const float* w_upv  = (const float*)d_in[4];
  const float* w_out  = (const float*)d_in[5];
  const float* b_out  = (const float*)d_in[6];
  float* out = (float*)d_out;

  char* ws = (char*)d_ws;
  size_t off = 0;
  auto alloc = [&](size_t elems) {
    void* p = ws + off; off += elems * 2; off = (off + 255) & ~(size_t)255; return p;
  };
  unsigned short* xb   = (unsigned short*)alloc((size_t)MROWS * EMB);
  unsigned short* wqb  = (unsigned short*)alloc((size_t)EMB * EMB);
  unsigned short* wdb  = (unsigned short*)alloc((size_t)LATENT * EMB);
  unsigned short* wkb  = (unsigned short*)alloc((size_t)EMB * LATENT);
  unsigned short* wvb  = (unsigned short*)alloc((size_t)EMB * LATENT);
  unsigned short* wob  = (unsigned short*)alloc((size_t)EMB * EMB);
  unsigned short* qb   = (unsigned short*)alloc((size_t)MROWS * EMB);
  unsigned short* latb = (unsigned short*)alloc((size_t)MROWS * LATENT);
  unsigned short* kb   = (unsigned short*)alloc((size_t)MROWS * EMB);
  unsigned short* vtb  = (unsigned short*)alloc((size_t)EMB * MROWS);  // V^T [2048][4096]
  unsigned short* ctxb = xb;   // xb dead after first two GEMMs; reuse for ctx

  auto cvt = [&](const float* s, unsigned short* d, size_t n) {
    int n4 = (int)(n / 4);
    int blocks = (n4 + 255) / 256; if (blocks > 1024) blocks = 1024;
    cvt_kernel<<<dim3(blocks), dim3(256), 0, stream>>>(s, d, n4);
  };
  cvt(x,      xb,  (size_t)MROWS * EMB);
  cvt(w_q,    wqb, (size_t)EMB * EMB);
  cvt(w_down, wdb, (size_t)LATENT * EMB);
  cvt(w_upk,  wkb, (size_t)EMB * LATENT);
  cvt(w_upv,  wvb, (size_t)EMB * LATENT);
  cvt(w_out,  wob, (size_t)EMB * EMB);

  gemm_bt<0><<<dim3(EMB/BN,    MROWS/BM), 256, 0, stream>>>(xb,   wqb, qb,   nullptr, MROWS, EMB,    EMB);
  gemm_bt<0><<<dim3(LATENT/BN, MROWS/BM), 256, 0, stream>>>(xb,   wdb, latb, nullptr, MROWS, LATENT, EMB);
  gemm_bt<0><<<dim3(EMB/BN,    MROWS/BM), 256, 0, stream>>>(latb, wkb, kb,   nullptr, MROWS, EMB,    LATENT);
  // V^T = w_up_v @ latent^T : [EMB][MROWS]
  gemm_bt<0><<<dim3(MROWS/BN,  EMB/BM),   256, 0, stream>>>(wvb,  latb, vtb, nullptr, EMB,   MROWS,  LATENT);

  attn3_kernel<<<dim3(NQT3/2, HEADS, BATCH), 256, 0, stream>>>(qb, kb, vtb, ctxb);

  gemm_bt<1><<<dim3(EMB/BN, MROWS/BM), 256, 0, stream>>>(ctxb, wob, (void*)out, b_out, MROWS, EMB, EMB);
}

// Round 6
// 411.093 us; speedup vs baseline: 1.5719x; 1.1064x over previous
//
#include <hip/hip_runtime.h>
#include <hip/hip_bf16.h>

#define EMB 2048
#define HEADS 16
#define HDIM 128
#define LATENT 512
#define BATCH 2
#define SEQ 2048
#define MROWS (BATCH*SEQ)   // 4096

typedef __attribute__((ext_vector_type(4))) float f32x4;
typedef __attribute__((ext_vector_type(8))) short s16x8;

__device__ __forceinline__ unsigned short f2bf(float f) {
  __hip_bfloat16 h = __float2bfloat16(f);
  union { __hip_bfloat16 h; unsigned short u; } c; c.h = h; return c.u;
}

#define GLOAD_LDS16(g, l) \
  __builtin_amdgcn_global_load_lds((const __attribute__((address_space(1))) unsigned int*)(g), \
                                   (__attribute__((address_space(3))) unsigned int*)(l), 16, 0, 0)

// ---------------- fp32 -> bf16 conversion ----------------
__global__ void cvt_kernel(const float* __restrict__ src, unsigned short* __restrict__ dst, int n4) {
  int i = blockIdx.x * blockDim.x + threadIdx.x;
  int stride = gridDim.x * blockDim.x;
  for (; i < n4; i += stride) {
    float4 v = reinterpret_cast<const float4*>(src)[i];
    ushort4 o;
    o.x = f2bf(v.x); o.y = f2bf(v.y); o.z = f2bf(v.z); o.w = f2bf(v.w);
    reinterpret_cast<ushort4*>(dst)[i] = o;
  }
}

// ---------------- GEMM m97-style (kept for latent proj only) ----------------
#define BM 128
#define BN 128
#define BK 32

template<int OUTF32>
__global__ __launch_bounds__(256) void gemm_bt(
    const unsigned short* __restrict__ A, const unsigned short* __restrict__ B,
    void* __restrict__ C, const float* __restrict__ bias, int M, int N, int K)
{
  __shared__ __align__(16) unsigned short sA[BM][BK];
  __shared__ __align__(16) unsigned short sB[BN][BK];
  const int tid  = threadIdx.x;
  const int lane = tid & 63, wave = tid >> 6;
  const int wm = wave >> 1, wn = wave & 1;
  const int lrow = lane & 15, kgrp = lane >> 4;

  const int gx = gridDim.x;
  const int nwg = gx * gridDim.y;
  const int orig = blockIdx.y * gx + blockIdx.x;
  const int chunk = nwg >> 3;
  const int sw = (orig & 7) * chunk + (orig >> 3);
  const long bm = (long)(sw / gx) * BM, bn = (long)(sw % gx) * BN;

  const int srow = tid >> 2;
  const int scol = (tid & 3) * 8;

  f32x4 zero4 = {0.f, 0.f, 0.f, 0.f};
  f32x4 acc[4][4];
  #pragma unroll
  for (int i = 0; i < 4; ++i)
    #pragma unroll
    for (int j = 0; j < 4; ++j) acc[i][j] = zero4;

  const unsigned short* ga = A + (bm + srow) * (long)K + scol;
  const unsigned short* gb = B + (bn + srow) * (long)K + scol;

  for (int k0 = 0; k0 < K; k0 += BK) {
    GLOAD_LDS16(ga + k0,                 &sA[srow][scol]);
    GLOAD_LDS16(ga + 64*(long)K + k0,    &sA[srow + 64][scol]);
    GLOAD_LDS16(gb + k0,                 &sB[srow][scol]);
    GLOAD_LDS16(gb + 64*(long)K + k0,    &sB[srow + 64][scol]);
    __syncthreads();

    s16x8 aF[4], bF[4];
    #pragma unroll
    for (int i = 0; i < 4; ++i) {
      aF[i] = *reinterpret_cast<const s16x8*>(&sA[wm*64 + i*16 + lrow][kgrp*8]);
      bF[i] = *reinterpret_cast<const s16x8*>(&sB[wn*64 + i*16 + lrow][kgrp*8]);
    }
    #pragma unroll
    for (int i = 0; i < 4; ++i)
      #pragma unroll
      for (int j = 0; j < 4; ++j)
        acc[i][j] = __builtin_amdgcn_mfma_f32_16x16x32_bf16(aF[i], bF[j], acc[i][j], 0, 0, 0);
    __syncthreads();
  }

  #pragma unroll
  for (int i = 0; i < 4; ++i) {
    #pragma unroll
    for (int j = 0; j < 4; ++j) {
      long row = bm + wm*64 + i*16 + kgrp*4;
      long col = bn + wn*64 + j*16 + lrow;
      if (OUTF32) {
        float* Cf = (float*)C;
        float bv = bias[col];
        #pragma unroll
        for (int r = 0; r < 4; ++r) Cf[(row + r) * (long)N + col] = acc[i][j][r] + bv;
      } else {
        unsigned short* Cb = (unsigned short*)C;
        #pragma unroll
        for (int r = 0; r < 4; ++r) Cb[(row + r) * (long)N + col] = f2bf(acc[i][j][r]);
      }
    }
  }
}

// ---------------- GEMM-256: 256x128 tile, BK=64, 8 waves, dbuf LDS, swizzled ----------------
// C[M,N] = A[M,K]*B[N,K]^T. Grid (N/128, M/256), 512 threads.
// LDS 96KB dynamic: sA[2][256*64], sB[2][128*64]; rows of 128B, byte ^= ((row&7)<<4) swizzle.
// One barrier per K-64 tile (T3 minimum recipe): stage(t+1) -> compute(t) -> sync(drain).
#define G2_LDS (96*1024)

template<int OUTF32>
__global__ __launch_bounds__(512, 1) void gemm256(
    const unsigned short* __restrict__ A, const unsigned short* __restrict__ B,
    void* __restrict__ C, const float* __restrict__ bias, int M, int N, int K)
{
  extern __shared__ char smem[];
  const int tid  = threadIdx.x;
  const int lane = tid & 63, wave = tid >> 6;
  const int wm = wave >> 1, wn = wave & 1;      // 4 M-waves x 2 N-waves, 64x64 each
  const int lrow = lane & 15, kgrp = lane >> 4;

  const int gx = gridDim.x;                     // N/128
  const int nwg = gx * gridDim.y;               // 256
  const int orig = blockIdx.y * gx + blockIdx.x;
  const int chunk = nwg >> 3;
  const int sw = (orig & 7) * chunk + (orig >> 3);
  const long bm = (long)(sw / gx) * 256, bn = (long)(sw % gx) * 128;

  // staging: thread t handles row t/8 (+R*64), 16B slot (t%8)*16, source pre-swizzled
  const int strow = tid >> 3;                   // 0..63
  const int scolB = ((tid & 7) * 16) ^ ((strow & 7) << 4);  // swizzled source col, bytes
  const unsigned short* gaS = A + (bm + strow) * (long)K + (scolB >> 1);
  const unsigned short* gbS = B + (bn + strow) * (long)K + (scolB >> 1);

  // frag read: byte col for k-half kh, swizzled by lrow
  int fcol[2];
  #pragma unroll
  for (int kh = 0; kh < 2; ++kh) fcol[kh] = (kh * 64 + kgrp * 16) ^ ((lrow & 7) << 4);

  f32x4 zero4 = {0.f, 0.f, 0.f, 0.f};
  f32x4 acc[4][4];
  #pragma unroll
  for (int i = 0; i < 4; ++i)
    #pragma unroll
    for (int j = 0; j < 4; ++j) acc[i][j] = zero4;

  const int NT = K >> 6;
  auto stage = [&](int cur, int t) {
    const long k0 = (long)t * 64;
    unsigned short* sa = (unsigned short*)(smem) + cur * 16384 + tid * 8;
    unsigned short* sb = (unsigned short*)(smem + 65536) + cur * 8192 + tid * 8;
    #pragma unroll
    for (int R = 0; R < 4; ++R) GLOAD_LDS16(gaS + (R * 64) * (long)K + k0, sa + R * 4096);
    #pragma unroll
    for (int R = 0; R < 2; ++R) GLOAD_LDS16(gbS + (R * 64) * (long)K + k0, sb + R * 4096);
  };

  stage(0, 0);
  __syncthreads();

  int cur = 0;
  for (int t = 0; t < NT; ++t) {
    if (t + 1 < NT) stage(cur ^ 1, t + 1);
    const char* sa = smem + cur * 32768;
    const char* sb = smem + 65536 + cur * 16384;
    #pragma unroll
    for (int kh = 0; kh < 2; ++kh) {
      s16x8 aF[4], bF[4];
      #pragma unroll
      for (int i = 0; i < 4; ++i)
        aF[i] = *reinterpret_cast<const s16x8*>(sa + (wm*64 + i*16 + lrow) * 128 + fcol[kh]);
      #pragma unroll
      for (int j = 0; j < 4; ++j)
        bF[j] = *reinterpret_cast<const s16x8*>(sb + (wn*64 + j*16 + lrow) * 128 + fcol[kh]);
      __builtin_amdgcn_s_setprio(1);
      #pragma unroll
      for (int i = 0; i < 4; ++i)
        #pragma unroll
        for (int j = 0; j < 4; ++j)
          acc[i][j] = __builtin_amdgcn_mfma_f32_16x16x32_bf16(aF[i], bF[j], acc[i][j], 0, 0, 0);
      __builtin_amdgcn_s_setprio(0);
    }
    __syncthreads();   // drains vmcnt (stage t+1) + lgkm; buffers swap safely
    cur ^= 1;
  }

  #pragma unroll
  for (int i = 0; i < 4; ++i) {
    #pragma unroll
    for (int j = 0; j < 4; ++j) {
      long row = bm + wm*64 + i*16 + kgrp*4;
      long col = bn + wn*64 + j*16 + lrow;
      if (OUTF32) {
        float* Cf = (float*)C;
        float bv = bias[col];
        #pragma unroll
        for (int r = 0; r < 4; ++r) Cf[(row + r) * (long)N + col] = acc[i][j][r] + bv;
      } else {
        unsigned short* Cb = (unsigned short*)C;
        #pragma unroll
        for (int r = 0; r < 4; ++r) Cb[(row + r) * (long)N + col] = f2bf(acc[i][j][r]);
      }
    }
  }
}

// ---------------- causal flash attention v4 ----------------
// Flat grid 512; decode colocates all 16 pr-blocks of one (b,h) onto one XCD.
// 4 waves x 16 q-rows; pairs {31-pr, pr}; K LDS-swizzled dbuf; V^T from global (L2).
#define KVB 64
#define QTB 64
#define NQT3 (SEQ/QTB)   // 32

__global__ __launch_bounds__(256, 2) void attn4_kernel(
    const unsigned short* __restrict__ Q, const unsigned short* __restrict__ Kg,
    const unsigned short* __restrict__ Vt, unsigned short* __restrict__ CTX)
{
  // XCD-colocating decode: id = (g&7) + 8*((g>>3)*16 + pr), g = h + 16*b
  const int bid = blockIdx.x;
  const int rest = bid >> 3;
  const int pr = rest & 15;
  const int g = (bid & 7) + 8 * (rest >> 4);
  const int h = g & 15, b = g >> 4;

  const int tid = threadIdx.x, w = tid >> 6, lane = tid & 63;
  const int lrow = lane & 15, kgrp = lane >> 4;
  const size_t bS = (size_t)b * SEQ;

  __shared__ __align__(16) unsigned short sK[2][KVB * HDIM];  // 32 KB swizzled
  __shared__ __align__(16) unsigned short sP[4][16][72];      // 9 KB per-wave P

  const int krow  = tid >> 4;
  const int kcolB = ((tid & 15) * 16) ^ (((tid >> 4) & 7) << 4);
  const unsigned short* kst_g = Kg + (bS + krow) * EMB + h * HDIM + (kcolB >> 1);

  const int swz = (lrow & 7) << 4;
  int cc[4];
  #pragma unroll
  for (int kk = 0; kk < 4; ++kk) cc[kk] = ((kk * 64 + kgrp * 16) ^ swz) >> 1;

  const float C = 0.12751742f;  // log2(e)/sqrt(128)
  const float THR = 11.5f;
  f32x4 zero4 = {0.f, 0.f, 0.f, 0.f};
  s16x8 onesF;
  #pragma unroll
  for (int i = 0; i < 8; ++i) onesF[i] = (short)0x3F80;  // bf16 1.0

  const int qts[2] = {NQT3 - 1 - pr, pr};
  for (int ps = 0; ps < 2; ++ps) {
    const int qt = qts[ps];
    const int nt = qt + 1;
    const int qw = qt * QTB + w * 16;

    s16x8 qF[4];
    #pragma unroll
    for (int kk = 0; kk < 4; ++kk)
      qF[kk] = *reinterpret_cast<const s16x8*>(
          Q + (bS + qw + lrow) * EMB + h * HDIM + kk * 32 + kgrp * 8);

    f32x4 o[8];
    #pragma unroll
    for (int dt = 0; dt < 8; ++dt) o[dt] = zero4;
    float rm[4], rl[4];
    #pragma unroll
    for (int r = 0; r < 4; ++r) { rm[r] = -1.0e30f; rl[r] = 0.f; }

    __syncthreads();
    {
      unsigned short* l0 = &sK[0][0] + tid * 8;
      #pragma unroll
      for (int R = 0; R < 4; ++R) GLOAD_LDS16(kst_g + (size_t)R * 16 * EMB, l0 + R * 2048);
    }

    for (int j = 0; j < nt; ++j) {
      __syncthreads();
      const int kv0 = j * KVB;
      if (j + 1 < nt) {
        const unsigned short* gs = kst_g + (size_t)(j + 1) * KVB * EMB;
        unsigned short* ls = &sK[(j + 1) & 1][0] + tid * 8;
        #pragma unroll
        for (int R = 0; R < 4; ++R) GLOAD_LDS16(gs + (size_t)R * 16 * EMB, ls + R * 2048);
      }

      s16x8 vF[2][8];
      #pragma unroll
      for (int hf = 0; hf < 2; ++hf)
        #pragma unroll
        for (int dt = 0; dt < 8; ++dt)
          vF[hf][dt] = *reinterpret_cast<const s16x8*>(
              Vt + (size_t)(h * HDIM + dt * 16 + lrow) * MROWS + bS + kv0 + hf * 32 + kgrp * 8);

      const unsigned short* kb = &sK[j & 1][0];
      f32x4 sc[4];
      #pragma unroll
      for (int kvg = 0; kvg < 4; ++kvg) sc[kvg] = zero4;
      __builtin_amdgcn_s_setprio(1);
      #pragma unroll
      for (int kvg = 0; kvg < 4; ++kvg) {
        const int rb = (kvg * 16 + lrow) * HDIM;
        #pragma unroll
        for (int kk = 0; kk < 4; ++kk) {
          s16x8 kF = *reinterpret_cast<const s16x8*>(kb + rb + cc[kk]);
          sc[kvg] = __builtin_amdgcn_mfma_f32_16x16x32_bf16(qF[kk], kF, sc[kvg], 0, 0, 0);
        }
      }
      __builtin_amdgcn_s_setprio(0);

      const bool needm = (kv0 + 63 > qw);
      float sv[4][4];
      #pragma unroll
      for (int kvg = 0; kvg < 4; ++kvg)
        #pragma unroll
        for (int r = 0; r < 4; ++r) {
          float s = sc[kvg][r];
          if (needm) {
            int qq  = qw + kgrp * 4 + r;
            int col = kv0 + kvg * 16 + lrow;
            s = (col <= qq) ? s : -3.0e38f;
          }
          sv[kvg][r] = s;
        }
      float tm[4];
      #pragma unroll
      for (int r = 0; r < 4; ++r)
        tm[r] = fmaxf(fmaxf(sv[0][r], sv[1][r]), fmaxf(sv[2][r], sv[3][r]));
      #pragma unroll
      for (int m = 1; m < 16; m <<= 1)
        #pragma unroll
        for (int r = 0; r < 4; ++r) tm[r] = fmaxf(tm[r], __shfl_xor(tm[r], m));

      float d = tm[0] * C - rm[0];
      #pragma unroll
      for (int r = 1; r < 4; ++r) d = fmaxf(d, tm[r] * C - rm[r]);
      const bool skip = __all(d <= THR);

      float mn[4];
      #pragma unroll
      for (int r = 0; r < 4; ++r) mn[r] = skip ? rm[r] : fmaxf(rm[r], tm[r] * C);

      #pragma unroll
      for (int r = 0; r < 4; ++r) {
        float p0 = exp2f(fmaf(sv[0][r], C, -mn[r]));
        float p1 = exp2f(fmaf(sv[1][r], C, -mn[r]));
        float p2 = exp2f(fmaf(sv[2][r], C, -mn[r]));
        float p3 = exp2f(fmaf(sv[3][r], C, -mn[r]));
        const int qrow = kgrp * 4 + r;
        sP[w][qrow][ 0 + lrow] = f2bf(p0);
        sP[w][qrow][16 + lrow] = f2bf(p1);
        sP[w][qrow][32 + lrow] = f2bf(p2);
        sP[w][qrow][48 + lrow] = f2bf(p3);
      }
      if (!skip) {
        #pragma unroll
        for (int r = 0; r < 4; ++r) {
          float corr = exp2f(rm[r] - mn[r]);
          rm[r] = mn[r];
          rl[r] *= corr;
          #pragma unroll
          for (int dt = 0; dt < 8; ++dt) o[dt][r] *= corr;
        }
      }

      // PV + MFMA row-sum (replaces sum butterfly): D(psum)[q][*] = sum_k P[q][k]
      s16x8 pF[2];
      #pragma unroll
      for (int hf = 0; hf < 2; ++hf)
        pF[hf] = *reinterpret_cast<const s16x8*>(&sP[w][lrow][hf * 32 + kgrp * 8]);
      f32x4 psum = zero4;
      __builtin_amdgcn_s_setprio(1);
      psum = __builtin_amdgcn_mfma_f32_16x16x32_bf16(pF[0], onesF, psum, 0, 0, 0);
      psum = __builtin_amdgcn_mfma_f32_16x16x32_bf16(pF[1], onesF, psum, 0, 0, 0);
      #pragma unroll
      for (int dt = 0; dt < 8; ++dt) {
        o[dt] = __builtin_amdgcn_mfma_f32_16x16x32_bf16(pF[0], vF[0][dt], o[dt], 0, 0, 0);
        o[dt] = __builtin_amdgcn_mfma_f32_16x16x32_bf16(pF[1], vF[1][dt], o[dt], 0, 0, 0);
      }
      __builtin_amdgcn_s_setprio(0);
      #pragma unroll
      for (int r = 0; r < 4; ++r) rl[r] += psum[r];
    }

    float iv[4];
    #pragma unroll
    for (int r = 0; r < 4; ++r) iv[r] = 1.0f / rl[r];
    #pragma unroll
    for (int dt = 0; dt < 8; ++dt)
      #pragma unroll
      for (int r = 0; r < 4; ++r)
        CTX[(bS + qw + kgrp * 4 + r) * EMB + h * HDIM + dt * 16 + lrow] =
            f2bf(o[dt][r] * iv[r]);
  }
}

// ---------------- launcher ----------------
extern "C" void kernel_launch(void* const* d_in, const int* in_sizes, int n_in,
                              void* d_out, int out_size, void* d_ws, size_t ws_size,
                              hipStream_t stream)
{
  const float* x      = (const float*)d_in[0];
  const float* w_q    = (const float*)d_in[1];
  const float* w_down = (const float*)d_in[2];
  const float* w_upk  = (const float*)d_in[3];
  const float* w_upv  = (const float*)d_in[4];
  const float* w_out  = (const float*)d_in[5];
  const float* b_out  = (const float*)d_in[6];
  float* out = (float*)d_out;

  // allow 96KB dynamic LDS (host-side attr set; capture-safe, idempotent)
  static bool attr_done = false;
  if (!attr_done) {
    hipFuncSetAttribute((const void*)gemm256<0>, hipFuncAttributeMaxDynamicSharedMemorySize, G2_LDS);
    hipFuncSetAttribute((const void*)gemm256<1>, hipFuncAttributeMaxDynamicSharedMemorySize, G2_LDS);
    attr_done = true;
  }

  char* ws = (char*)d_ws;
  size_t off = 0;
  auto alloc = [&](size_t elems) {
    void* p = ws + off; off += elems * 2; off = (off + 255) & ~(size_t)255; return p;
  };
  unsigned short* xb   = (unsigned short*)alloc((size_t)MROWS * EMB);
  unsigned short* wqb  = (unsigned short*)alloc((size_t)EMB * EMB);
  unsigned short* wdb  = (unsigned short*)alloc((size_t)LATENT * EMB);
  unsigned short* wkb  = (unsigned short*)alloc((size_t)EMB * LATENT);
  unsigned short* wvb  = (unsigned short*)alloc((size_t)EMB * LATENT);
  unsigned short* wob  = (unsigned short*)alloc((size_t)EMB * EMB);
  unsigned short* qb   = (unsigned short*)alloc((size_t)MROWS * EMB);
  unsigned short* latb = (unsigned short*)alloc((size_t)MROWS * LATENT);
  unsigned short* kb   = (unsigned short*)alloc((size_t)MROWS * EMB);
  unsigned short* vtb  = (unsigned short*)alloc((size_t)EMB * MROWS);  // V^T [2048][4096]
  unsigned short* ctxb = xb;

  auto cvt = [&](const float* s, unsigned short* d, size_t n) {
    int n4 = (int)(n / 4);
    int blocks = (n4 + 255) / 256; if (blocks > 1024) blocks = 1024;
    cvt_kernel<<<dim3(blocks), dim3(256), 0, stream>>>(s, d, n4);
  };
  cvt(x,      xb,  (size_t)MROWS * EMB);
  cvt(w_q,    wqb, (size_t)EMB * EMB);
  cvt(w_down, wdb, (size_t)LATENT * EMB);
  cvt(w_upk,  wkb, (size_t)EMB * LATENT);
  cvt(w_upv,  wvb, (size_t)EMB * LATENT);
  cvt(w_out,  wob, (size_t)EMB * EMB);

  // Q-proj: 4096x2048, K=2048  -> gemm256 grid (16,16)=256
  gemm256<0><<<dim3(EMB/128, MROWS/256), 512, G2_LDS, stream>>>(xb, wqb, qb, nullptr, MROWS, EMB, EMB);
  // latent: 4096x512, K=2048 -> m97 kernel (grid 4x32=128)
  gemm_bt<0><<<dim3(LATENT/BN, MROWS/BM), 256, 0, stream>>>(xb, wdb, latb, nullptr, MROWS, LATENT, EMB);
  // K-up: 4096x2048, K=512 -> gemm256
  gemm256<0><<<dim3(EMB/128, MROWS/256), 512, G2_LDS, stream>>>(latb, wkb, kb, nullptr, MROWS, EMB, LATENT);
  // V^T: 2048x4096, K=512 -> gemm256 grid (32,8)=256
  gemm256<0><<<dim3(MROWS/128, EMB/256), 512, G2_LDS, stream>>>(wvb, latb, vtb, nullptr, EMB, MROWS, LATENT);

  attn4_kernel<<<dim3(512, 1, 1), 256, 0, stream>>>(qb, kb, vtb, ctxb);

  // out-proj: 4096x2048, K=2048, f32+bias -> gemm256
  gemm256<1><<<dim3(EMB/128, MROWS/256), 512, G2_LDS, stream>>>(ctxb, wob, (void*)out, b_out, MROWS, EMB, EMB);
}

// Round 7
// 404.619 us; speedup vs baseline: 1.5971x; 1.0160x over previous
//
#include <hip/hip_runtime.h>
#include <hip/hip_bf16.h>

#define EMB 2048
#define HEADS 16
#define HDIM 128
#define LATENT 512
#define BATCH 2
#define SEQ 2048
#define MROWS (BATCH*SEQ)   // 4096

typedef __attribute__((ext_vector_type(4))) float f32x4;
typedef __attribute__((ext_vector_type(8))) short s16x8;

__device__ __forceinline__ unsigned short f2bf(float f) {
  __hip_bfloat16 h = __float2bfloat16(f);
  union { __hip_bfloat16 h; unsigned short u; } c; c.h = h; return c.u;
}

#define GLOAD_LDS16(g, l) \
  __builtin_amdgcn_global_load_lds((const __attribute__((address_space(1))) unsigned int*)(g), \
                                   (__attribute__((address_space(3))) unsigned int*)(l), 16, 0, 0)

// ---------------- fp32 -> bf16 conversion ----------------
__global__ void cvt_kernel(const float* __restrict__ src, unsigned short* __restrict__ dst, int n4) {
  int i = blockIdx.x * blockDim.x + threadIdx.x;
  int stride = gridDim.x * blockDim.x;
  for (; i < n4; i += stride) {
    float4 v = reinterpret_cast<const float4*>(src)[i];
    ushort4 o;
    o.x = f2bf(v.x); o.y = f2bf(v.y); o.z = f2bf(v.z); o.w = f2bf(v.w);
    reinterpret_cast<ushort4*>(dst)[i] = o;
  }
}

// ---------------- GEMM m97-style (latent proj only) ----------------
#define BM 128
#define BN 128
#define BK 32

template<int OUTF32>
__global__ __launch_bounds__(256) void gemm_bt(
    const unsigned short* __restrict__ A, const unsigned short* __restrict__ B,
    void* __restrict__ C, const float* __restrict__ bias, int M, int N, int K)
{
  __shared__ __align__(16) unsigned short sA[BM][BK];
  __shared__ __align__(16) unsigned short sB[BN][BK];
  const int tid  = threadIdx.x;
  const int lane = tid & 63, wave = tid >> 6;
  const int wm = wave >> 1, wn = wave & 1;
  const int lrow = lane & 15, kgrp = lane >> 4;

  const int gx = gridDim.x;
  const int nwg = gx * gridDim.y;
  const int orig = blockIdx.y * gx + blockIdx.x;
  const int chunk = nwg >> 3;
  const int sw = (orig & 7) * chunk + (orig >> 3);
  const long bm = (long)(sw / gx) * BM, bn = (long)(sw % gx) * BN;

  const int srow = tid >> 2;
  const int scol = (tid & 3) * 8;

  f32x4 zero4 = {0.f, 0.f, 0.f, 0.f};
  f32x4 acc[4][4];
  #pragma unroll
  for (int i = 0; i < 4; ++i)
    #pragma unroll
    for (int j = 0; j < 4; ++j) acc[i][j] = zero4;

  const unsigned short* ga = A + (bm + srow) * (long)K + scol;
  const unsigned short* gb = B + (bn + srow) * (long)K + scol;

  for (int k0 = 0; k0 < K; k0 += BK) {
    GLOAD_LDS16(ga + k0,                 &sA[srow][scol]);
    GLOAD_LDS16(ga + 64*(long)K + k0,    &sA[srow + 64][scol]);
    GLOAD_LDS16(gb + k0,                 &sB[srow][scol]);
    GLOAD_LDS16(gb + 64*(long)K + k0,    &sB[srow + 64][scol]);
    __syncthreads();

    s16x8 aF[4], bF[4];
    #pragma unroll
    for (int i = 0; i < 4; ++i) {
      aF[i] = *reinterpret_cast<const s16x8*>(&sA[wm*64 + i*16 + lrow][kgrp*8]);
      bF[i] = *reinterpret_cast<const s16x8*>(&sB[wn*64 + i*16 + lrow][kgrp*8]);
    }
    #pragma unroll
    for (int i = 0; i < 4; ++i)
      #pragma unroll
      for (int j = 0; j < 4; ++j)
        acc[i][j] = __builtin_amdgcn_mfma_f32_16x16x32_bf16(aF[i], bF[j], acc[i][j], 0, 0, 0);
    __syncthreads();
  }

  #pragma unroll
  for (int i = 0; i < 4; ++i) {
    #pragma unroll
    for (int j = 0; j < 4; ++j) {
      long row = bm + wm*64 + i*16 + kgrp*4;
      long col = bn + wn*64 + j*16 + lrow;
      if (OUTF32) {
        float* Cf = (float*)C;
        float bv = bias[col];
        #pragma unroll
        for (int r = 0; r < 4; ++r) Cf[(row + r) * (long)N + col] = acc[i][j][r] + bv;
      } else {
        unsigned short* Cb = (unsigned short*)C;
        #pragma unroll
        for (int r = 0; r < 4; ++r) Cb[(row + r) * (long)N + col] = f2bf(acc[i][j][r]);
      }
    }
  }
}

// ---------------- GEMM-256: 256x128 tile, BK=64, 8 waves, dbuf LDS, swizzled ----------------
#define G2_LDS (96*1024)

template<int OUTF32>
__global__ __launch_bounds__(512, 1) void gemm256(
    const unsigned short* __restrict__ A, const unsigned short* __restrict__ B,
    void* __restrict__ C, const float* __restrict__ bias, int M, int N, int K)
{
  extern __shared__ char smem[];
  const int tid  = threadIdx.x;
  const int lane = tid & 63, wave = tid >> 6;
  const int wm = wave >> 1, wn = wave & 1;
  const int lrow = lane & 15, kgrp = lane >> 4;

  const int gx = gridDim.x;
  const int nwg = gx * gridDim.y;
  const int orig = blockIdx.y * gx + blockIdx.x;
  const int chunk = nwg >> 3;
  const int sw = (orig & 7) * chunk + (orig >> 3);
  const long bm = (long)(sw / gx) * 256, bn = (long)(sw % gx) * 128;

  const int strow = tid >> 3;
  const int scolB = ((tid & 7) * 16) ^ ((strow & 7) << 4);
  const unsigned short* gaS = A + (bm + strow) * (long)K + (scolB >> 1);
  const unsigned short* gbS = B + (bn + strow) * (long)K + (scolB >> 1);

  int fcol[2];
  #pragma unroll
  for (int kh = 0; kh < 2; ++kh) fcol[kh] = (kh * 64 + kgrp * 16) ^ ((lrow & 7) << 4);

  f32x4 zero4 = {0.f, 0.f, 0.f, 0.f};
  f32x4 acc[4][4];
  #pragma unroll
  for (int i = 0; i < 4; ++i)
    #pragma unroll
    for (int j = 0; j < 4; ++j) acc[i][j] = zero4;

  const int NT = K >> 6;
  auto stage = [&](int cur, int t) {
    const long k0 = (long)t * 64;
    unsigned short* sa = (unsigned short*)(smem) + cur * 16384 + tid * 8;
    unsigned short* sb = (unsigned short*)(smem + 65536) + cur * 8192 + tid * 8;
    #pragma unroll
    for (int R = 0; R < 4; ++R) GLOAD_LDS16(gaS + (R * 64) * (long)K + k0, sa + R * 4096);
    #pragma unroll
    for (int R = 0; R < 2; ++R) GLOAD_LDS16(gbS + (R * 64) * (long)K + k0, sb + R * 4096);
  };

  stage(0, 0);
  __syncthreads();

  int cur = 0;
  for (int t = 0; t < NT; ++t) {
    if (t + 1 < NT) stage(cur ^ 1, t + 1);
    const char* sa = smem + cur * 32768;
    const char* sb = smem + 65536 + cur * 16384;
    #pragma unroll
    for (int kh = 0; kh < 2; ++kh) {
      s16x8 aF[4], bF[4];
      #pragma unroll
      for (int i = 0; i < 4; ++i)
        aF[i] = *reinterpret_cast<const s16x8*>(sa + (wm*64 + i*16 + lrow) * 128 + fcol[kh]);
      #pragma unroll
      for (int j = 0; j < 4; ++j)
        bF[j] = *reinterpret_cast<const s16x8*>(sb + (wn*64 + j*16 + lrow) * 128 + fcol[kh]);
      __builtin_amdgcn_s_setprio(1);
      #pragma unroll
      for (int i = 0; i < 4; ++i)
        #pragma unroll
        for (int j = 0; j < 4; ++j)
          acc[i][j] = __builtin_amdgcn_mfma_f32_16x16x32_bf16(aF[i], bF[j], acc[i][j], 0, 0, 0);
      __builtin_amdgcn_s_setprio(0);
    }
    __syncthreads();
    cur ^= 1;
  }

  #pragma unroll
  for (int i = 0; i < 4; ++i) {
    #pragma unroll
    for (int j = 0; j < 4; ++j) {
      long row = bm + wm*64 + i*16 + kgrp*4;
      long col = bn + wn*64 + j*16 + lrow;
      if (OUTF32) {
        float* Cf = (float*)C;
        float bv = bias[col];
        #pragma unroll
        for (int r = 0; r < 4; ++r) Cf[(row + r) * (long)N + col] = acc[i][j][r] + bv;
      } else {
        unsigned short* Cb = (unsigned short*)C;
        #pragma unroll
        for (int r = 0; r < 4; ++r) Cb[(row + r) * (long)N + col] = f2bf(acc[i][j][r]);
      }
    }
  }
}

// ---------------- causal flash attention v5: swapped QK^T, lane-local softmax ----------------
// Flat grid 512, XCD-colocating decode. 4 waves x 16 q-rows; pairs {31-pr, pr}.
// mfma(K,Q): D col=lane&15=q, row=kgrp*4+r=kv -> each lane owns ONE q row:
// max/sum = in-lane trees + 2 scalar shuffles (vs 16 bpermute butterfly).
#define KVB 64
#define QTB 64
#define NQT3 (SEQ/QTB)   // 32

__global__ __launch_bounds__(256, 2) void attn5_kernel(
    const unsigned short* __restrict__ Q, const unsigned short* __restrict__ Kg,
    const unsigned short* __restrict__ Vt, unsigned short* __restrict__ CTX)
{
  const int bid = blockIdx.x;
  const int rest = bid >> 3;
  const int pr = rest & 15;
  const int g = (bid & 7) + 8 * (rest >> 4);
  const int h = g & 15, b = g >> 4;

  const int tid = threadIdx.x, w = tid >> 6, lane = tid & 63;
  const int lrow = lane & 15, kgrp = lane >> 4;
  const int qloc = lrow;           // this lane's q row (swapped layout)
  const size_t bS = (size_t)b * SEQ;

  __shared__ __align__(16) unsigned short sK[2][KVB * HDIM];
  __shared__ __align__(16) unsigned short sP[4][16][72];

  const int krow  = tid >> 4;
  const int kcolB = ((tid & 15) * 16) ^ (((tid >> 4) & 7) << 4);
  const unsigned short* kst_g = Kg + (bS + krow) * EMB + h * HDIM + (kcolB >> 1);

  const int swz = (lrow & 7) << 4;
  int cc[4];
  #pragma unroll
  for (int kk = 0; kk < 4; ++kk) cc[kk] = ((kk * 64 + kgrp * 16) ^ swz) >> 1;

  const float C = 0.12751742f;  // log2(e)/sqrt(128)
  const float THR = 11.5f;
  f32x4 zero4 = {0.f, 0.f, 0.f, 0.f};

  const int qts[2] = {NQT3 - 1 - pr, pr};
  for (int ps = 0; ps < 2; ++ps) {
    const int qt = qts[ps];
    const int nt = qt + 1;
    const int qw = qt * QTB + w * 16;
    const int q_abs = qw + qloc;

    s16x8 qF[4];
    #pragma unroll
    for (int kk = 0; kk < 4; ++kk)
      qF[kk] = *reinterpret_cast<const s16x8*>(
          Q + (bS + qw + lrow) * EMB + h * HDIM + kk * 32 + kgrp * 8);

    f32x4 o[8];
    #pragma unroll
    for (int dt = 0; dt < 8; ++dt) o[dt] = zero4;
    float rm = -1.0e30f, rl = 0.f;   // scalar: stats for q = qloc

    __syncthreads();
    {
      unsigned short* l0 = &sK[0][0] + tid * 8;
      #pragma unroll
      for (int R = 0; R < 4; ++R) GLOAD_LDS16(kst_g + (size_t)R * 16 * EMB, l0 + R * 2048);
    }

    for (int j = 0; j < nt; ++j) {
      __syncthreads();
      const int kv0 = j * KVB;
      if (j + 1 < nt) {
        const unsigned short* gs = kst_g + (size_t)(j + 1) * KVB * EMB;
        unsigned short* ls = &sK[(j + 1) & 1][0] + tid * 8;
        #pragma unroll
        for (int R = 0; R < 4; ++R) GLOAD_LDS16(gs + (size_t)R * 16 * EMB, ls + R * 2048);
      }

      s16x8 vF[2][8];
      #pragma unroll
      for (int hf = 0; hf < 2; ++hf)
        #pragma unroll
        for (int dt = 0; dt < 8; ++dt)
          vF[hf][dt] = *reinterpret_cast<const s16x8*>(
              Vt + (size_t)(h * HDIM + dt * 16 + lrow) * MROWS + bS + kv0 + hf * 32 + kgrp * 8);

      // QK^T swapped: mfma(K, Q) -> col=q, row=kv
      const unsigned short* kb = &sK[j & 1][0];
      f32x4 sc[4];
      #pragma unroll
      for (int kvg = 0; kvg < 4; ++kvg) sc[kvg] = zero4;
      __builtin_amdgcn_s_setprio(1);
      #pragma unroll
      for (int kvg = 0; kvg < 4; ++kvg) {
        const int rb = (kvg * 16 + lrow) * HDIM;
        #pragma unroll
        for (int kk = 0; kk < 4; ++kk) {
          s16x8 kF = *reinterpret_cast<const s16x8*>(kb + rb + cc[kk]);
          sc[kvg] = __builtin_amdgcn_mfma_f32_16x16x32_bf16(kF, qF[kk], sc[kvg], 0, 0, 0);
        }
      }
      __builtin_amdgcn_s_setprio(0);

      // mask: kv index = kv0 + kvg*16 + kgrp*4 + r, q = q_abs (lane-uniform)
      const bool needm = (kv0 + 63 > qw);
      float sv[4][4];
      #pragma unroll
      for (int kvg = 0; kvg < 4; ++kvg)
        #pragma unroll
        for (int r = 0; r < 4; ++r) {
          float s = sc[kvg][r];
          if (needm) {
            int kv = kv0 + kvg * 16 + kgrp * 4 + r;
            s = (kv <= q_abs) ? s : -3.0e38f;
          }
          sv[kvg][r] = s;
        }

      // in-lane max over 16 + 2 scalar cross-shuffles
      float m01 = fmaxf(fmaxf(sv[0][0], sv[0][1]), fmaxf(sv[0][2], sv[0][3]));
      float m11 = fmaxf(fmaxf(sv[1][0], sv[1][1]), fmaxf(sv[1][2], sv[1][3]));
      float m21 = fmaxf(fmaxf(sv[2][0], sv[2][1]), fmaxf(sv[2][2], sv[2][3]));
      float m31 = fmaxf(fmaxf(sv[3][0], sv[3][1]), fmaxf(sv[3][2], sv[3][3]));
      float tm = fmaxf(fmaxf(m01, m11), fmaxf(m21, m31));
      tm = fmaxf(tm, __shfl_xor(tm, 16));
      tm = fmaxf(tm, __shfl_xor(tm, 32));

      const float dchk = tm * C - rm;
      const bool skip = __all(dchk <= THR);
      const float mn = skip ? rm : fmaxf(rm, tm * C);

      // exp + in-lane sum + P pack/write (8 x ds_write_b32, 2-way banks = free)
      float p[4][4];
      float ts = 0.f;
      #pragma unroll
      for (int kvg = 0; kvg < 4; ++kvg) {
        #pragma unroll
        for (int r = 0; r < 4; ++r) {
          p[kvg][r] = exp2f(fmaf(sv[kvg][r], C, -mn));
          ts += p[kvg][r];
        }
      }
      unsigned int* sPw = reinterpret_cast<unsigned int*>(&sP[w][qloc][0]);
      #pragma unroll
      for (int kvg = 0; kvg < 4; ++kvg) {
        unsigned int lo = (unsigned int)f2bf(p[kvg][0]) | ((unsigned int)f2bf(p[kvg][1]) << 16);
        unsigned int hi = (unsigned int)f2bf(p[kvg][2]) | ((unsigned int)f2bf(p[kvg][3]) << 16);
        sPw[kvg * 8 + kgrp * 2 + 0] = lo;
        sPw[kvg * 8 + kgrp * 2 + 1] = hi;
      }
      ts += __shfl_xor(ts, 16);
      ts += __shfl_xor(ts, 32);

      const float corr = exp2f(rm - mn);   // == 1 when skip
      rl = rl * corr + ts;
      rm = mn;

      if (!skip) {
        // fetch corr for q = kgrp*4+r (lane (lane&48)|q' holds it)
        float c4[4];
        #pragma unroll
        for (int r = 0; r < 4; ++r)
          c4[r] = __shfl(corr, (lane & 48) | (kgrp * 4 + r));
        #pragma unroll
        for (int dt = 0; dt < 8; ++dt)
          #pragma unroll
          for (int r = 0; r < 4; ++r) o[dt][r] *= c4[r];
      }

      // PV: A = P (LDS, per-wave), B = V^T (regs)
      s16x8 pF[2];
      #pragma unroll
      for (int hf = 0; hf < 2; ++hf)
        pF[hf] = *reinterpret_cast<const s16x8*>(&sP[w][lrow][hf * 32 + kgrp * 8]);
      __builtin_amdgcn_s_setprio(1);
      #pragma unroll
      for (int dt = 0; dt < 8; ++dt) {
        o[dt] = __builtin_amdgcn_mfma_f32_16x16x32_bf16(pF[0], vF[0][dt], o[dt], 0, 0, 0);
        o[dt] = __builtin_amdgcn_mfma_f32_16x16x32_bf16(pF[1], vF[1][dt], o[dt], 0, 0, 0);
      }
      __builtin_amdgcn_s_setprio(0);
    }

    // epilogue: iv for q = kgrp*4+r fetched from owning lane
    const float ivq = 1.0f / rl;
    float iv[4];
    #pragma unroll
    for (int r = 0; r < 4; ++r)
      iv[r] = __shfl(ivq, (lane & 48) | (kgrp * 4 + r));
    #pragma unroll
    for (int dt = 0; dt < 8; ++dt)
      #pragma unroll
      for (int r = 0; r < 4; ++r)
        CTX[(bS + qw + kgrp * 4 + r) * EMB + h * HDIM + dt * 16 + lrow] =
            f2bf(o[dt][r] * iv[r]);
  }
}

// ---------------- launcher ----------------
extern "C" void kernel_launch(void* const* d_in, const int* in_sizes, int n_in,
                              void* d_out, int out_size, void* d_ws, size_t ws_size,
                              hipStream_t stream)
{
  const float* x      = (const float*)d_in[0];
  const float* w_q    = (const float*)d_in[1];
  const float* w_down = (const float*)d_in[2];
  const float* w_upk  = (const float*)d_in[3];
  const float* w_upv  = (const float*)d_in[4];
  const float* w_out  = (const float*)d_in[5];
  const float* b_out  = (const float*)d_in[6];
  float* out = (float*)d_out;

  static bool attr_done = false;
  if (!attr_done) {
    hipFuncSetAttribute((const void*)gemm256<0>, hipFuncAttributeMaxDynamicSharedMemorySize, G2_LDS);
    hipFuncSetAttribute((const void*)gemm256<1>, hipFuncAttributeMaxDynamicSharedMemorySize, G2_LDS);
    attr_done = true;
  }

  char* ws = (char*)d_ws;
  size_t off = 0;
  auto alloc = [&](size_t elems) {
    void* p = ws + off; off += elems * 2; off = (off + 255) & ~(size_t)255; return p;
  };
  unsigned short* xb   = (unsigned short*)alloc((size_t)MROWS * EMB);
  unsigned short* wqb  = (unsigned short*)alloc((size_t)EMB * EMB);
  unsigned short* wdb  = (unsigned short*)alloc((size_t)LATENT * EMB);
  unsigned short* wkb  = (unsigned short*)alloc((size_t)EMB * LATENT);
  unsigned short* wvb  = (unsigned short*)alloc((size_t)EMB * LATENT);
  unsigned short* wob  = (unsigned short*)alloc((size_t)EMB * EMB);
  unsigned short* qb   = (unsigned short*)alloc((size_t)MROWS * EMB);
  unsigned short* latb = (unsigned short*)alloc((size_t)MROWS * LATENT);
  unsigned short* kb   = (unsigned short*)alloc((size_t)MROWS * EMB);
  unsigned short* vtb  = (unsigned short*)alloc((size_t)EMB * MROWS);  // V^T [2048][4096]
  unsigned short* ctxb = xb;

  auto cvt = [&](const float* s, unsigned short* d, size_t n) {
    int n4 = (int)(n / 4);
    int blocks = (n4 + 255) / 256; if (blocks > 1024) blocks = 1024;
    cvt_kernel<<<dim3(blocks), dim3(256), 0, stream>>>(s, d, n4);
  };
  cvt(x,      xb,  (size_t)MROWS * EMB);
  cvt(w_q,    wqb, (size_t)EMB * EMB);
  cvt(w_down, wdb, (size_t)LATENT * EMB);
  cvt(w_upk,  wkb, (size_t)EMB * LATENT);
  cvt(w_upv,  wvb, (size_t)EMB * LATENT);
  cvt(w_out,  wob, (size_t)EMB * EMB);

  gemm256<0><<<dim3(EMB/128, MROWS/256), 512, G2_LDS, stream>>>(xb, wqb, qb, nullptr, MROWS, EMB, EMB);
  gemm_bt<0><<<dim3(LATENT/BN, MROWS/BM), 256, 0, stream>>>(xb, wdb, latb, nullptr, MROWS, LATENT, EMB);
  gemm256<0><<<dim3(EMB/128, MROWS/256), 512, G2_LDS, stream>>>(latb, wkb, kb, nullptr, MROWS, EMB, LATENT);
  gemm256<0><<<dim3(MROWS/128, EMB/256), 512, G2_LDS, stream>>>(wvb, latb, vtb, nullptr, EMB, MROWS, LATENT);

  attn5_kernel<<<dim3(512, 1, 1), 256, 0, stream>>>(qb, kb, vtb, ctxb);

  gemm256<1><<<dim3(EMB/128, MROWS/256), 512, G2_LDS, stream>>>(ctxb, wob, (void*)out, b_out, MROWS, EMB, EMB);
}